// Round 3
// baseline (56.431 us; speedup 1.0000x reference)
//
#include <hip/hip_runtime.h>

#define HID 64
#define VOC 64
#define NSLOT 8
#define NB 256
#define SEQL 2048

// ---------------------------------------------------------------------------
// Single fused kernel, 256 blocks x 256 threads.
//  blocks 0..63 / wave 0 : produce vocab row b (h, score, q) -> global ws
//  all blocks            : histogram of own seq row (overlaps producers)
//  spin on cnt0==64      : device-scope atomic flag + acquire fence
//  then rank -> greedy top-8 multiset -> attention -> entropy gate -> logits
//  last block (cnt1)     : deterministic tree-reduce of entropies -> mean
// ---------------------------------------------------------------------------
__global__ __launch_bounds__(256) void fused_kernel(
    const int* __restrict__ seq,
    const float* __restrict__ embed, const float* __restrict__ w1, const float* __restrict__ b1,
    const float* __restrict__ w2, const float* __restrict__ b2,
    const float* __restrict__ ln_g, const float* __restrict__ ln_b,
    const float* __restrict__ gate_w, const float* __restrict__ gate_b,
    const float* __restrict__ q_w, const float* __restrict__ q_b,
    const float* __restrict__ out_w, const float* __restrict__ out_b,
    float* __restrict__ wsH, float* __restrict__ wsQ, float* __restrict__ wsScore,
    float* __restrict__ entw, int* __restrict__ cnt,
    float* __restrict__ out)
{
    const int t = threadIdx.x, b = blockIdx.x;
    const int lane = t & 63, wave = t >> 6;

    __shared__ int   hist[VOC];
    __shared__ float sscore[VOC];
    __shared__ float hlds[VOC * (HID + 1)];   // +1 pad: conflict-free row reads
    __shared__ float sqv[HID];
    __shared__ int   sorder[VOC];
    __shared__ int   svids[NSLOT];
    __shared__ float sla[NSLOT];
    __shared__ float seff[NSLOT];
    __shared__ int   shvlast;
    __shared__ int   sfin;
    __shared__ float sred[4];

    if (t < VOC) hist[t] = 0;
    if (t == 0) shvlast = seq[(size_t)b * SEQL + SEQL - 1];
    __syncthreads();

    // ---- producer: blocks 0..63, wave 0 computes vocab row v = b ----------
    if (b < VOC && wave == 0) {
        const int v = b;
        const float e = embed[v * HID + lane];
        float fa = b1[lane], fb = b1[HID + lane];
#pragma unroll
        for (int i = 0; i < HID; ++i) {
            const float ei = __shfl(e, i);
            fa = fmaf(ei, w1[i * 2 * HID + lane], fa);
            fb = fmaf(ei, w1[i * 2 * HID + HID + lane], fb);
        }
        fa = fmaxf(fa, 0.0f);
        fb = fmaxf(fb, 0.0f);
        float z = e + b2[lane];
#pragma unroll
        for (int j = 0; j < HID; ++j)
            z = fmaf(__shfl(fa, j), w2[j * HID + lane], z);
#pragma unroll
        for (int j = 0; j < HID; ++j)
            z = fmaf(__shfl(fb, j), w2[(HID + j) * HID + lane], z);
        float s = z;
#pragma unroll
        for (int m = 32; m; m >>= 1) s += __shfl_xor(s, m);
        const float mu = s * (1.0f / HID);
        const float d = z - mu;
        float vs = d * d;
#pragma unroll
        for (int m = 32; m; m >>= 1) vs += __shfl_xor(vs, m);
        const float inv = 1.0f / sqrtf(vs * (1.0f / HID) + 1e-5f);
        const float h = d * inv * ln_g[lane] + ln_b[lane];
        wsH[v * HID + lane] = h;
        float sc = h * gate_w[lane];
#pragma unroll
        for (int m = 32; m; m >>= 1) sc += __shfl_xor(sc, m);
        if (lane == 0) wsScore[v] = sc + gate_b[0];
        float q = q_b[lane];
#pragma unroll
        for (int k = 0; k < HID; ++k)
            q = fmaf(__shfl(h, k), q_w[k * HID + lane], q);
        wsQ[v * HID + lane] = q;
        __threadfence();                       // release: publish row
        if (lane == 0) atomicAdd(&cnt[0], 1);
    }

    // ---- all blocks: histogram of this row's 2048 ids (int4 loads) --------
    const int4* row4 = (const int4*)(seq + (size_t)b * SEQL);
    for (int p = t; p < SEQL / 4; p += 256) {
        const int4 vv = row4[p];
        atomicAdd(&hist[vv.x], 1);
        atomicAdd(&hist[vv.y], 1);
        atomicAdd(&hist[vv.z], 1);
        atomicAdd(&hist[vv.w], 1);
    }
    __syncthreads();

    // ---- wait for all 64 vocab rows ---------------------------------------
    if (t == 0) {
        while (atomicOr(&cnt[0], 0) < VOC) __builtin_amdgcn_s_sleep(2);
    }
    __syncthreads();
    __threadfence();                           // acquire: see producer stores

    if (t < VOC) sscore[t] = wsScore[t];
    for (int p = t; p < VOC * HID; p += 256)
        hlds[(p >> 6) * (HID + 1) + (p & 63)] = wsH[p];
    if (t < VOC) sqv[t] = wsQ[shvlast * HID + t];
    __syncthreads();

    // ---- rank ids by score desc (tie -> lower id) -------------------------
    if (t < VOC) {
        const float sv = sscore[t];
        int r = 0;
        for (int u = 0; u < VOC; ++u) {
            const float su = sscore[u];
            if (su > sv || (su == sv && u < t)) ++r;
        }
        sorder[r] = t;
    }
    __syncthreads();

    // ---- greedy top-8 multiset with multiplicity --------------------------
    if (t == 0) {
        int r = NSLOT, n = 0, pos = 0;
        while (r > 0) {
            const int v = sorder[pos++];
            int c = hist[v];
            if (c > r) c = r;
            for (int k = 0; k < c; ++k) svids[n++] = v;
            r -= c;
        }
    }
    __syncthreads();

    // ---- attention logits: 8 lanes, one slot each -------------------------
    if (t < NSLOT) {
        const float* hr = &hlds[svids[t] * (HID + 1)];
        float acc = 0.0f;
#pragma unroll
        for (int i = 0; i < HID; ++i) acc = fmaf(hr[i], sqv[i], acc);
        sla[t] = acc * 0.125f;                 // 1/sqrt(64)
    }
    __syncthreads();

    // ---- softmax + entropy gate (tiny, serial) ----------------------------
    if (t == 0) {
        float m = -1e30f;
        for (int k = 0; k < NSLOT; ++k) m = fmaxf(m, sla[k]);
        float e[NSLOT], s = 0.0f;
        for (int k = 0; k < NSLOT; ++k) { e[k] = expf(sla[k] - m); s += e[k]; }
        const float invs = 1.0f / s;
        float ent = 0.0f;
        for (int k = 0; k < NSLOT; ++k) {
            const float a = e[k] * invs;
            ent -= a * logf(a + 1e-9f);
        }
        const float high = (ent > 1.5f) ? 1.0f : 0.0f;
        for (int k = 0; k < NSLOT; ++k)
            seff[k] = (1.0f - high) * (e[k] * invs) + high * (1.0f / NSLOT);
        entw[b] = ent;
    }
    __syncthreads();

    // ---- ctx -> logits (wave 0) -------------------------------------------
    if (t < VOC) {
        float ctx = 0.0f;
#pragma unroll
        for (int k = 0; k < NSLOT; ++k)
            ctx = fmaf(seff[k], hlds[svids[k] * (HID + 1) + t], ctx);
        float acc = out_b[t];
#pragma unroll
        for (int i = 0; i < HID; ++i)
            acc = fmaf(__shfl(ctx, i), out_w[i * VOC + t], acc);
        out[(size_t)b * VOC + t] = acc;
    }
    __syncthreads();

    // ---- last block: deterministic tree-reduce of entropies -> mean -------
    if (t == 0) {
        __threadfence();                       // release entw[b]
        const int old = atomicAdd(&cnt[1], 1);
        sfin = (old == NB - 1) ? 1 : 0;
    }
    __syncthreads();
    if (sfin) {
        __threadfence();                       // acquire all entw
        float v = entw[t];
#pragma unroll
        for (int m = 32; m; m >>= 1) v += __shfl_xor(v, m);
        if (lane == 0) sred[wave] = v;
        __syncthreads();
        if (t == 0)
            out[(size_t)NB * VOC] =
                (sred[0] + sred[1] + sred[2] + sred[3]) * (1.0f / NB);
    }
}

extern "C" void kernel_launch(void* const* d_in, const int* in_sizes, int n_in,
                              void* d_out, int out_size, void* d_ws, size_t ws_size,
                              hipStream_t stream) {
    const int*   seq    = (const int*)  d_in[0];
    const float* embed  = (const float*)d_in[1];
    const float* w1     = (const float*)d_in[2];
    const float* b1     = (const float*)d_in[3];
    const float* w2     = (const float*)d_in[4];
    const float* b2     = (const float*)d_in[5];
    const float* ln_g   = (const float*)d_in[6];
    const float* ln_b   = (const float*)d_in[7];
    const float* gate_w = (const float*)d_in[8];
    const float* gate_b = (const float*)d_in[9];
    const float* q_w    = (const float*)d_in[10];
    const float* q_b    = (const float*)d_in[11];
    const float* out_w  = (const float*)d_in[12];
    const float* out_b  = (const float*)d_in[13];
    float* out = (float*)d_out;

    float* ws      = (float*)d_ws;
    float* wsH     = ws;              // 4096 floats
    float* wsQ     = ws + 4096;       // 4096 floats
    float* wsScore = ws + 8192;       // 64 floats
    float* entw    = ws + 8256;       // 256 floats
    int*   cnt     = (int*)(ws + 8512);  // 2 ints (sync counters)

    hipMemsetAsync(cnt, 0, 2 * sizeof(int), stream);
    fused_kernel<<<NB, 256, 0, stream>>>(seq, embed, w1, b1, w2, b2, ln_g, ln_b,
                                         gate_w, gate_b, q_w, q_b, out_w, out_b,
                                         wsH, wsQ, wsScore, entw, cnt, out);
}

// Round 4
// 23.955 us; speedup vs baseline: 2.3557x; 2.3557x over previous
//
#include <hip/hip_runtime.h>

#define HID 64
#define VOC 64
#define NSLOT 8
#define NB 256
#define SEQL 2048

// ---------------------------------------------------------------------------
// Kernel A: one wave (64-thread block) per vocab id v. Lane i holds element i
// of every per-row vector; cross-lane operands via __shfl (register-only).
// Outputs: wsH[v][:], wsQ[v][:], wsScore[v]. Block 0 also zeroes the entropy
// accumulator (next kernel atomicAdds into it; kernel boundary orders this).
// ---------------------------------------------------------------------------
__global__ __launch_bounds__(64) void vocab_kernel(
    const float* __restrict__ embed, const float* __restrict__ w1, const float* __restrict__ b1,
    const float* __restrict__ w2, const float* __restrict__ b2,
    const float* __restrict__ ln_g, const float* __restrict__ ln_b,
    const float* __restrict__ gate_w, const float* __restrict__ gate_b,
    const float* __restrict__ q_w, const float* __restrict__ q_b,
    float* __restrict__ wsH, float* __restrict__ wsQ, float* __restrict__ wsScore,
    float* __restrict__ ent_out)
{
    const int lane = threadIdx.x;
    const int v = blockIdx.x;

    if (v == 0 && lane == 0) ent_out[0] = 0.0f;

    const float e = embed[v * HID + lane];

    // FFN layer 1: lane handles hidden units j=lane and j=lane+64 (2 indep chains).
    float fa = b1[lane], fb = b1[HID + lane];
#pragma unroll
    for (int i = 0; i < HID; ++i) {
        const float ei = __shfl(e, i);
        fa = fmaf(ei, w1[i * 2 * HID + lane], fa);
        fb = fmaf(ei, w1[i * 2 * HID + HID + lane], fb);
    }
    fa = fmaxf(fa, 0.0f);
    fb = fmaxf(fb, 0.0f);

    // FFN layer 2 + residual: lane holds z[i=lane]. Two partial chains for ILP.
    float za = e + b2[lane], zb = 0.0f;
#pragma unroll
    for (int j = 0; j < HID; ++j) {
        za = fmaf(__shfl(fa, j), w2[j * HID + lane], za);
        zb = fmaf(__shfl(fb, j), w2[(HID + j) * HID + lane], zb);
    }
    const float z = za + zb;

    // LayerNorm via wave butterfly reductions.
    float s = z;
#pragma unroll
    for (int m = 32; m; m >>= 1) s += __shfl_xor(s, m);
    const float mu = s * (1.0f / HID);
    const float d = z - mu;
    float vs = d * d;
#pragma unroll
    for (int m = 32; m; m >>= 1) vs += __shfl_xor(vs, m);
    const float inv = 1.0f / sqrtf(vs * (1.0f / HID) + 1e-5f);
    const float h = d * inv * ln_g[lane] + ln_b[lane];
    wsH[v * HID + lane] = h;

    // Gate score (wave reduce).
    float sc = h * gate_w[lane];
#pragma unroll
    for (int m = 32; m; m >>= 1) sc += __shfl_xor(sc, m);
    if (lane == 0) wsScore[v] = sc + gate_b[0];

    // Query row: q[v][i=lane] = q_b[i] + sum_k h[k] * q_w[k][i].
    float q = q_b[lane];
#pragma unroll
    for (int k = 0; k < HID; ++k)
        q = fmaf(__shfl(h, k), q_w[k * HID + lane], q);
    wsQ[v * HID + lane] = q;
}

// ---------------------------------------------------------------------------
// Kernel B: one block per batch row. Histogram -> rank -> greedy top-8
// multiset -> attention -> entropy gate -> logits; entropy mean folded in as
// one device-scope atomicAdd per block (scalar zeroed by kernel A).
// ---------------------------------------------------------------------------
__global__ __launch_bounds__(256) void batch_kernel(
    const int* __restrict__ seq,
    const float* __restrict__ out_w, const float* __restrict__ out_b,
    const float* __restrict__ wsH, const float* __restrict__ wsQ,
    const float* __restrict__ wsScore,
    float* __restrict__ out, float* __restrict__ ent_out)
{
    __shared__ int hist[VOC];
    __shared__ float sscore[VOC];
    __shared__ float hlds[VOC * (HID + 1)];   // +1 pad: conflict-free reads
    __shared__ float sqv[HID];
    __shared__ int sorder[VOC];
    __shared__ int svids[NSLOT];
    __shared__ float sla[NSLOT];
    __shared__ float seff[NSLOT];
    __shared__ int shvlast;

    const int t = threadIdx.x;
    const int b = blockIdx.x;

    if (t < VOC) { hist[t] = 0; sscore[t] = wsScore[t]; }
    if (t == 0) shvlast = seq[(size_t)b * SEQL + SEQL - 1];
    __syncthreads();

    // Histogram of the 2048 vocab ids (int4 loads, LDS atomics).
    const int4* row4 = (const int4*)(seq + (size_t)b * SEQL);
    for (int p = t; p < SEQL / 4; p += 256) {
        const int4 vv = row4[p];
        atomicAdd(&hist[vv.x], 1);
        atomicAdd(&hist[vv.y], 1);
        atomicAdd(&hist[vv.z], 1);
        atomicAdd(&hist[vv.w], 1);
    }
    // Stage h into padded LDS (coalesced).
    for (int p = t; p < VOC * HID; p += 256)
        hlds[(p >> 6) * (HID + 1) + (p & 63)] = wsH[p];
    __syncthreads();

    // Rank ids by score desc (tie -> lower id); fetch q row of last token.
    if (t < VOC) {
        const float sv = sscore[t];
        int r = 0;
        for (int u = 0; u < VOC; ++u) {
            const float su = sscore[u];
            if (su > sv || (su == sv && u < t)) ++r;
        }
        sorder[r] = t;
        sqv[t] = wsQ[shvlast * HID + t];
    }
    __syncthreads();

    // Greedy top-8 multiset by descending score with multiplicity.
    if (t == 0) {
        int r = NSLOT, n = 0, pos = 0;
        while (r > 0) {
            const int v = sorder[pos++];
            int c = hist[v];
            if (c > r) c = r;
            for (int k = 0; k < c; ++k) svids[n++] = v;
            r -= c;
        }
    }
    __syncthreads();

    // Attention logits: 8 lanes, one slot each.
    if (t < NSLOT) {
        const float* hr = &hlds[svids[t] * (HID + 1)];
        float acc = 0.0f;
#pragma unroll
        for (int i = 0; i < HID; ++i) acc = fmaf(hr[i], sqv[i], acc);
        sla[t] = acc * 0.125f;                 // 1/sqrt(64)
    }
    __syncthreads();

    // Softmax + entropy gate; one atomicAdd for the batch-mean entropy.
    if (t == 0) {
        float m = -1e30f;
        for (int k = 0; k < NSLOT; ++k) m = fmaxf(m, sla[k]);
        float e[NSLOT], s = 0.0f;
        for (int k = 0; k < NSLOT; ++k) { e[k] = expf(sla[k] - m); s += e[k]; }
        const float invs = 1.0f / s;
        float ent = 0.0f;
        for (int k = 0; k < NSLOT; ++k) {
            const float a = e[k] * invs;
            ent -= a * logf(a + 1e-9f);
        }
        const float high = (ent > 1.5f) ? 1.0f : 0.0f;
        for (int k = 0; k < NSLOT; ++k)
            seff[k] = (1.0f - high) * (e[k] * invs) + high * (1.0f / NSLOT);
        atomicAdd(ent_out, ent * (1.0f / NB));
    }
    __syncthreads();

    // ctx -> logits (wave 0; shfl broadcast of ctx, coalesced 256B store).
    if (t < VOC) {
        float ctx = 0.0f;
#pragma unroll
        for (int k = 0; k < NSLOT; ++k)
            ctx = fmaf(seff[k], hlds[svids[k] * (HID + 1) + t], ctx);
        float acc = out_b[t];
#pragma unroll
        for (int i = 0; i < HID; ++i)
            acc = fmaf(__shfl(ctx, i), out_w[i * VOC + t], acc);
        out[(size_t)b * VOC + t] = acc;
    }
}

extern "C" void kernel_launch(void* const* d_in, const int* in_sizes, int n_in,
                              void* d_out, int out_size, void* d_ws, size_t ws_size,
                              hipStream_t stream) {
    const int*   seq    = (const int*)  d_in[0];
    const float* embed  = (const float*)d_in[1];
    const float* w1     = (const float*)d_in[2];
    const float* b1     = (const float*)d_in[3];
    const float* w2     = (const float*)d_in[4];
    const float* b2     = (const float*)d_in[5];
    const float* ln_g   = (const float*)d_in[6];
    const float* ln_b   = (const float*)d_in[7];
    const float* gate_w = (const float*)d_in[8];
    const float* gate_b = (const float*)d_in[9];
    const float* q_w    = (const float*)d_in[10];
    const float* q_b    = (const float*)d_in[11];
    const float* out_w  = (const float*)d_in[12];
    const float* out_b  = (const float*)d_in[13];
    float* out = (float*)d_out;
    float* ent_out = out + (size_t)NB * VOC;

    float* ws      = (float*)d_ws;
    float* wsH     = ws;              // 4096 floats
    float* wsQ     = ws + 4096;       // 4096 floats
    float* wsScore = ws + 8192;       // 64 floats

    vocab_kernel<<<VOC, 64, 0, stream>>>(embed, w1, b1, w2, b2, ln_g, ln_b,
                                         gate_w, gate_b, q_w, q_b,
                                         wsH, wsQ, wsScore, ent_out);
    batch_kernel<<<NB, 256, 0, stream>>>(seq, out_w, out_b, wsH, wsQ, wsScore,
                                         out, ent_out);
}